// Round 3
// baseline (231.861 us; speedup 1.0000x reference)
//
#include <hip/hip_runtime.h>
#include <hip/hip_bf16.h>

// out[512, 65536] = inputs[512,256] @ features[65536,256]^T  (fp32 in/out)
// bf16 MFMA GEMM, C = A * B^T with A,B row-major [rows][K=256].
// fp32 -> bf16 conversion fused into LDS staging.
// R3: (a) XCD-aware block swizzle: the 4 M-blocks sharing a B-tile get
//     dispatch ids differing by 8 -> same XCD under round-robin -> B tile
//     served from that XCD's L2 (3/4 hits) instead of L3.
//     (b) nontemporal C stores (write-once, never read -> don't thrash L2).
//     (c) launch_bounds(256,3): ~170 VGPR budget, no spill risk (R2's cap of
//     128 was too tight for acc64+frags32+staging).

#define M_DIM 512
#define N_DIM 65536
#define K_DIM 256
#define BM 128
#define BN 128
#define BK 64
#define LDK (BK + 8)   // +8 bf16 (16B) pad: breaks 128B row stride, keeps 16B align

typedef __bf16 bf16x8 __attribute__((ext_vector_type(8)));
typedef float f32x4 __attribute__((ext_vector_type(4)));

__global__ __launch_bounds__(256, 3) void hm_gemm_bt(
    const float* __restrict__ A,   // inputs   [M][K]
    const float* __restrict__ B,   // features [N][K]
    float* __restrict__ C)         // out      [M][N]
{
    __shared__ __align__(16) __bf16 As[BM * LDK];
    __shared__ __align__(16) __bf16 Bs[BN * LDK];

    const int tid  = threadIdx.x;
    const int lane = tid & 63;
    const int wave = tid >> 6;            // 4 waves, 2x2 grid of 64x64 subtiles
    const int wm   = (wave >> 1) * 64;
    const int wn   = (wave & 1) * 64;

    // XCD swizzle: lid = q*32 + m*8 + yl  (q = y-group of 8, yl = y%8).
    // The 4 blocks {m=0..3} of one y have lids differing by 8 -> same XCD
    // under round-robin dispatch; 8 consecutive y's share an XCD window
    // (B working set 8 tiles * 128 rows * 1KB = 1MB << 4MB L2).
    const int lid = blockIdx.x;
    const int q   = lid >> 5;
    const int rem = lid & 31;
    const int mt  = rem >> 3;
    const int yt  = (q << 3) + (rem & 7);

    const int m0 = mt * BM;
    const int n0 = yt * BN;

    f32x4 acc[4][4];
    #pragma unroll
    for (int i = 0; i < 4; ++i)
        #pragma unroll
        for (int j = 0; j < 4; ++j)
            acc[i][j] = f32x4{0.f, 0.f, 0.f, 0.f};

    // MFMA 16x16x32 bf16 operand mapping:
    //   a: A[m = lane&15][k = (lane>>4)*8 + j]
    //   b: B^T[n = lane&15][k = (lane>>4)*8 + j]   (features are [N][K])
    //   d: C[row = (lane>>4)*4 + reg][col = lane&15]   (verified m89/m91)
    const int lrow = lane & 15;
    const int lk   = (lane >> 4) * 8;

    for (int k0 = 0; k0 < K_DIM; k0 += BK) {
        // ---- stage A tile: 128x64 fp32 -> bf16.  1024 chunks of 8 elems.
        #pragma unroll
        for (int i = 0; i < 4; ++i) {
            const int c   = i * 256 + tid;      // 0..1023
            const int row = c >> 3;             // BK/8 = 8 chunks per row
            const int kc  = (c & 7) * 8;
            const float* src = A + (m0 + row) * K_DIM + k0 + kc;
            f32x4 v0 = *(const f32x4*)(src);
            f32x4 v1 = *(const f32x4*)(src + 4);
            bf16x8 h;
            h[0] = (__bf16)v0[0]; h[1] = (__bf16)v0[1];
            h[2] = (__bf16)v0[2]; h[3] = (__bf16)v0[3];
            h[4] = (__bf16)v1[0]; h[5] = (__bf16)v1[1];
            h[6] = (__bf16)v1[2]; h[7] = (__bf16)v1[3];
            *(bf16x8*)&As[row * LDK + kc] = h;
        }
        // ---- stage B tile: 128x64 fp32 -> bf16
        #pragma unroll
        for (int i = 0; i < 4; ++i) {
            const int c   = i * 256 + tid;
            const int row = c >> 3;
            const int kc  = (c & 7) * 8;
            const float* src = B + (n0 + row) * K_DIM + k0 + kc;
            f32x4 v0 = *(const f32x4*)(src);
            f32x4 v1 = *(const f32x4*)(src + 4);
            bf16x8 h;
            h[0] = (__bf16)v0[0]; h[1] = (__bf16)v0[1];
            h[2] = (__bf16)v0[2]; h[3] = (__bf16)v0[3];
            h[4] = (__bf16)v1[0]; h[5] = (__bf16)v1[1];
            h[6] = (__bf16)v1[2]; h[7] = (__bf16)v1[3];
            *(bf16x8*)&Bs[row * LDK + kc] = h;
        }
        __syncthreads();

        #pragma unroll
        for (int ks = 0; ks < BK; ks += 32) {
            bf16x8 af[4], bfr[4];
            #pragma unroll
            for (int i = 0; i < 4; ++i)
                af[i] = *(const bf16x8*)&As[(wm + i * 16 + lrow) * LDK + ks + lk];
            #pragma unroll
            for (int j = 0; j < 4; ++j)
                bfr[j] = *(const bf16x8*)&Bs[(wn + j * 16 + lrow) * LDK + ks + lk];
            #pragma unroll
            for (int i = 0; i < 4; ++i)
                #pragma unroll
                for (int j = 0; j < 4; ++j)
                    acc[i][j] = __builtin_amdgcn_mfma_f32_16x16x32_bf16(
                        af[i], bfr[j], acc[i][j], 0, 0, 0);
        }
        __syncthreads();
    }

    // ---- epilogue: C[row = (lane>>4)*4 + r][col = lane&15]
    // nontemporal: C is write-once, never re-read -> keep it out of L2.
    const int crow = (lane >> 4) * 4;
    const int ccol = lane & 15;
    #pragma unroll
    for (int i = 0; i < 4; ++i) {
        #pragma unroll
        for (int j = 0; j < 4; ++j) {
            float* dst = C + (size_t)(m0 + wm + i * 16 + crow) * N_DIM
                           + (n0 + wn + j * 16 + ccol);
            #pragma unroll
            for (int r = 0; r < 4; ++r)
                __builtin_nontemporal_store(acc[i][j][r], dst + (size_t)r * N_DIM);
        }
    }
}

extern "C" void kernel_launch(void* const* d_in, const int* in_sizes, int n_in,
                              void* d_out, int out_size, void* d_ws, size_t ws_size,
                              hipStream_t stream) {
    // setup_inputs order: inputs, indexes, features, mIoU, IoU
    const float* inputs   = (const float*)d_in[0];
    const float* features = (const float*)d_in[2];
    float* out = (float*)d_out;

    dim3 grid((M_DIM / BM) * (N_DIM / BN));   // 2048, 1-D for XCD swizzle
    hipLaunchKernelGGL(hm_gemm_bt, grid, dim3(256), 0, stream,
                       inputs, features, out);
}

// Round 4
// 215.070 us; speedup vs baseline: 1.0781x; 1.0781x over previous
//
#include <hip/hip_runtime.h>
#include <hip/hip_bf16.h>

// out[512, 65536] = inputs[512,256] @ features[65536,256]^T  (fp32 in/out)
// R4: two-pass. Pass1 converts fp32->bf16 into d_ws (streaming, BW-bound).
// Pass2 is the m97-verified async GEMM: __builtin_amdgcn_global_load_lds
// width-16 staging (fire-and-forget -> no VGPR round-trip, deep MLP),
// unpadded LDS (required by the wave-uniform-base + lane*16 scatter rule).
// R3's NT stores + XCD swizzle regressed -> reverted (plain stores, 2-D grid).
// Fallback fused kernel if ws_size too small (branch constant per-run: graph-safe).

#define M_DIM 512
#define N_DIM 65536
#define K_DIM 256
#define BM 128
#define BN 128
#define BK 64

#define B_ELEMS (N_DIM * K_DIM)            // 16,777,216
#define A_ELEMS (M_DIM * K_DIM)            // 131,072
#define B_CHUNKS (B_ELEMS / 8)             // 2,097,152
#define A_CHUNKS (A_ELEMS / 8)             // 16,384
#define CVT_BLOCKS ((B_CHUNKS + A_CHUNKS) / 256)   // 8256

typedef __bf16 bf16x8 __attribute__((ext_vector_type(8)));
typedef float f32x4 __attribute__((ext_vector_type(4)));

#define GLOBAL_AS __attribute__((address_space(1)))
#define LDS_AS    __attribute__((address_space(3)))

// ---------------- Pass 1: fp32 -> bf16 convert ----------------
__global__ __launch_bounds__(256) void cvt_f32_bf16(
    const float* __restrict__ A, const float* __restrict__ B,
    __bf16* __restrict__ wsA, __bf16* __restrict__ wsB)
{
    const long c = (long)blockIdx.x * 256 + threadIdx.x;   // chunk of 8 elems
    const float* src;
    __bf16* dst;
    if (c < B_CHUNKS) { src = B + c * 8;              dst = wsB + c * 8; }
    else              { src = A + (c - B_CHUNKS) * 8; dst = wsA + (c - B_CHUNKS) * 8; }
    f32x4 v0 = *(const f32x4*)(src);
    f32x4 v1 = *(const f32x4*)(src + 4);
    bf16x8 h;
    h[0] = (__bf16)v0[0]; h[1] = (__bf16)v0[1];
    h[2] = (__bf16)v0[2]; h[3] = (__bf16)v0[3];
    h[4] = (__bf16)v1[0]; h[5] = (__bf16)v1[1];
    h[6] = (__bf16)v1[2]; h[7] = (__bf16)v1[3];
    *(bf16x8*)dst = h;
}

// ---------------- Pass 2: m97-style async-staged bf16 GEMM ----------------
__global__ __launch_bounds__(256, 3) void hm_gemm_async(
    const __bf16* __restrict__ A,   // [M][K] bf16
    const __bf16* __restrict__ B,   // [N][K] bf16
    float* __restrict__ C)          // [M][N]
{
    // unpadded: global_load_lds writes lane i at base + i*16B -> layout must be
    // exactly row-major 64 bf16 (128 B) per row.
    __shared__ __align__(16) __bf16 As[BM * BK];   // 16 KB
    __shared__ __align__(16) __bf16 Bs[BN * BK];   // 16 KB

    const int tid  = threadIdx.x;
    const int lane = tid & 63;
    const int wave = tid >> 6;            // 4 waves, 2x2 grid of 64x64 subtiles
    const int wm   = (wave >> 1) * 64;
    const int wn   = (wave & 1) * 64;

    const int m0 = blockIdx.x * BM;       // grid.x = 4
    const int n0 = blockIdx.y * BN;       // grid.y = 512

    // staging decomposition: one issue = 64 lanes * 16 B = 8 rows of 128 B.
    const int r8 = lane >> 3;             // row within the 8-row issue group
    const int c8 = lane & 7;              // 16B chunk within row

    f32x4 acc[4][4];
    #pragma unroll
    for (int i = 0; i < 4; ++i)
        #pragma unroll
        for (int j = 0; j < 4; ++j)
            acc[i][j] = f32x4{0.f, 0.f, 0.f, 0.f};

    const int lrow = lane & 15;
    const int lk   = (lane >> 4) * 8;

    for (int k0 = 0; k0 < K_DIM; k0 += BK) {
        // wave w stages rows w*32 .. w*32+31 of both tiles (4 issues each)
        #pragma unroll
        for (int j = 0; j < 4; ++j) {
            const int rb = wave * 32 + j * 8;
            const __bf16* ga = A + (size_t)(m0 + rb + r8) * K_DIM + k0 + c8 * 8;
            __builtin_amdgcn_global_load_lds(
                (const GLOBAL_AS void*)ga,
                (LDS_AS void*)(As + rb * BK), 16, 0, 0);
            const __bf16* gb = B + (size_t)(n0 + rb + r8) * K_DIM + k0 + c8 * 8;
            __builtin_amdgcn_global_load_lds(
                (const GLOBAL_AS void*)gb,
                (LDS_AS void*)(Bs + rb * BK), 16, 0, 0);
        }
        __syncthreads();   // compiler emits vmcnt(0) drain before barrier

        #pragma unroll
        for (int ks = 0; ks < BK; ks += 32) {
            bf16x8 af[4], bfr[4];
            #pragma unroll
            for (int i = 0; i < 4; ++i)
                af[i] = *(const bf16x8*)&As[(wm + i * 16 + lrow) * BK + ks + lk];
            #pragma unroll
            for (int j = 0; j < 4; ++j)
                bfr[j] = *(const bf16x8*)&Bs[(wn + j * 16 + lrow) * BK + ks + lk];
            #pragma unroll
            for (int i = 0; i < 4; ++i)
                #pragma unroll
                for (int j = 0; j < 4; ++j)
                    acc[i][j] = __builtin_amdgcn_mfma_f32_16x16x32_bf16(
                        af[i], bfr[j], acc[i][j], 0, 0, 0);
        }
        __syncthreads();
    }

    // epilogue: C[row = (lane>>4)*4 + r][col = lane&15]  (plain stores)
    const int crow = (lane >> 4) * 4;
    const int ccol = lane & 15;
    #pragma unroll
    for (int i = 0; i < 4; ++i) {
        #pragma unroll
        for (int j = 0; j < 4; ++j) {
            float* dst = C + (size_t)(m0 + wm + i * 16 + crow) * N_DIM
                           + (n0 + wn + j * 16 + ccol);
            #pragma unroll
            for (int r = 0; r < 4; ++r)
                dst[(size_t)r * N_DIM] = acc[i][j][r];
        }
    }
}

// ---------------- Fallback: R1 fused convert-while-staging kernel ----------------
#define LDK (BK + 8)
__global__ __launch_bounds__(256, 2) void hm_gemm_fused(
    const float* __restrict__ A, const float* __restrict__ B, float* __restrict__ C)
{
    __shared__ __align__(16) __bf16 As[BM * LDK];
    __shared__ __align__(16) __bf16 Bs[BN * LDK];
    const int tid = threadIdx.x, lane = tid & 63, wave = tid >> 6;
    const int wm = (wave >> 1) * 64, wn = (wave & 1) * 64;
    const int m0 = blockIdx.x * BM, n0 = blockIdx.y * BN;
    f32x4 acc[4][4];
    #pragma unroll
    for (int i = 0; i < 4; ++i)
        #pragma unroll
        for (int j = 0; j < 4; ++j) acc[i][j] = f32x4{0.f, 0.f, 0.f, 0.f};
    const int lrow = lane & 15, lk = (lane >> 4) * 8;
    for (int k0 = 0; k0 < K_DIM; k0 += BK) {
        #pragma unroll
        for (int i = 0; i < 4; ++i) {
            const int c = i * 256 + tid, row = c >> 3, kc = (c & 7) * 8;
            const float* src = A + (m0 + row) * K_DIM + k0 + kc;
            f32x4 v0 = *(const f32x4*)(src), v1 = *(const f32x4*)(src + 4);
            bf16x8 h;
            h[0] = (__bf16)v0[0]; h[1] = (__bf16)v0[1]; h[2] = (__bf16)v0[2]; h[3] = (__bf16)v0[3];
            h[4] = (__bf16)v1[0]; h[5] = (__bf16)v1[1]; h[6] = (__bf16)v1[2]; h[7] = (__bf16)v1[3];
            *(bf16x8*)&As[row * LDK + kc] = h;
        }
        #pragma unroll
        for (int i = 0; i < 4; ++i) {
            const int c = i * 256 + tid, row = c >> 3, kc = (c & 7) * 8;
            const float* src = B + (n0 + row) * K_DIM + k0 + kc;
            f32x4 v0 = *(const f32x4*)(src), v1 = *(const f32x4*)(src + 4);
            bf16x8 h;
            h[0] = (__bf16)v0[0]; h[1] = (__bf16)v0[1]; h[2] = (__bf16)v0[2]; h[3] = (__bf16)v0[3];
            h[4] = (__bf16)v1[0]; h[5] = (__bf16)v1[1]; h[6] = (__bf16)v1[2]; h[7] = (__bf16)v1[3];
            *(bf16x8*)&Bs[row * LDK + kc] = h;
        }
        __syncthreads();
        #pragma unroll
        for (int ks = 0; ks < BK; ks += 32) {
            bf16x8 af[4], bfr[4];
            #pragma unroll
            for (int i = 0; i < 4; ++i)
                af[i] = *(const bf16x8*)&As[(wm + i * 16 + lrow) * LDK + ks + lk];
            #pragma unroll
            for (int j = 0; j < 4; ++j)
                bfr[j] = *(const bf16x8*)&Bs[(wn + j * 16 + lrow) * LDK + ks + lk];
            #pragma unroll
            for (int i = 0; i < 4; ++i)
                #pragma unroll
                for (int j = 0; j < 4; ++j)
                    acc[i][j] = __builtin_amdgcn_mfma_f32_16x16x32_bf16(af[i], bfr[j], acc[i][j], 0, 0, 0);
        }
        __syncthreads();
    }
    const int crow = (lane >> 4) * 4, ccol = lane & 15;
    #pragma unroll
    for (int i = 0; i < 4; ++i)
        #pragma unroll
        for (int j = 0; j < 4; ++j) {
            float* dst = C + (size_t)(m0 + wm + i * 16 + crow) * N_DIM + (n0 + wn + j * 16 + ccol);
            #pragma unroll
            for (int r = 0; r < 4; ++r) dst[(size_t)r * N_DIM] = acc[i][j][r];
        }
}

extern "C" void kernel_launch(void* const* d_in, const int* in_sizes, int n_in,
                              void* d_out, int out_size, void* d_ws, size_t ws_size,
                              hipStream_t stream) {
    // setup_inputs order: inputs, indexes, features, mIoU, IoU
    const float* inputs   = (const float*)d_in[0];
    const float* features = (const float*)d_in[2];
    float* out = (float*)d_out;

    const size_t need = (size_t)(B_ELEMS + A_ELEMS) * sizeof(__bf16);  // ~33.8 MB
    if (ws_size >= need) {
        __bf16* wsB = (__bf16*)d_ws;
        __bf16* wsA = wsB + B_ELEMS;
        hipLaunchKernelGGL(cvt_f32_bf16, dim3(CVT_BLOCKS), dim3(256), 0, stream,
                           inputs, features, wsA, wsB);
        hipLaunchKernelGGL(hm_gemm_async, dim3(M_DIM / BM, N_DIM / BN), dim3(256), 0, stream,
                           wsA, wsB, out);
    } else {
        hipLaunchKernelGGL(hm_gemm_fused, dim3(M_DIM / BM, N_DIM / BN), dim3(256), 0, stream,
                           inputs, features, out);
    }
}